// Round 2
// baseline (233.707 us; speedup 1.0000x reference)
//
#include <hip/hip_runtime.h>
#include <stdint.h>

#define NN   4096
#define KIN  256
#define NH   8
#define FD   64
#define HFD  512
#define NC   2            // j-chunks (partial-sum splits)
#define BI   32           // i-rows per block in k3
#define JT   64           // j-tile
#define NT   ((NN / NC) / JT)

typedef __attribute__((ext_vector_type(4))) float  floatx4;
typedef __attribute__((ext_vector_type(8))) short  short8;

__device__ __forceinline__ unsigned short f2bf_rne(float x) {
    uint32_t u = __float_as_uint(x);
    u += 0x7FFFu + ((u >> 16) & 1u);
    return (unsigned short)(u >> 16);
}

// pack two fp32 -> two bf16 (truncate) into one dword: {hi[31:16], lo[31:16]}
__device__ __forceinline__ uint32_t packtrunc(float lo, float hi) {
    return (__float_as_uint(hi) & 0xFFFF0000u) | (__float_as_uint(lo) >> 16);
}

// ---- k1: Wh = h @ W (fp32 accurate); writes WhbT bf16 [HF][N] + e_srcT/e_dstT [H][N] ----
__global__ __launch_bounds__(256) void k1_front(
        const float* __restrict__ hmat, const float* __restrict__ Wmat,
        const float* __restrict__ a_src, const float* __restrict__ a_dst,
        unsigned short* __restrict__ whbT,
        float* __restrict__ esrcT, float* __restrict__ edstT) {
    __shared__ float As[64][36];       // stride 36: 16B-aligned rows, 2-way max bank alias
    __shared__ float Bs[32][64];
    __shared__ float scrS[64][16];
    __shared__ float scrD[64][16];
    const int tid = threadIdx.x;
    const int n0  = blockIdx.x * 64;
    const int hd  = blockIdx.y;        // one head's 64 cols per block-column
    const int hf0 = hd * 64;
    const int r0  = (tid >> 4) * 4;
    const int c0  = (tid & 15) * 4;
    float acc[4][4] = {};
    for (int k0 = 0; k0 < KIN; k0 += 32) {
        #pragma unroll
        for (int u = 0; u < 2; ++u) {
            const int v = tid * 2 + u;
            const int r = v >> 3, kk = (v & 7) * 4;
            *reinterpret_cast<float4*>(&As[r][kk]) =
                *reinterpret_cast<const float4*>(&hmat[(size_t)(n0 + r) * KIN + k0 + kk]);
        }
        #pragma unroll
        for (int u = 0; u < 2; ++u) {
            const int v = tid * 2 + u;
            const int kk = v >> 4, cc = (v & 15) * 4;
            *reinterpret_cast<float4*>(&Bs[kk][cc]) =
                *reinterpret_cast<const float4*>(&Wmat[(size_t)(k0 + kk) * HFD + hf0 + cc]);
        }
        __syncthreads();
        #pragma unroll
        for (int k = 0; k < 32; ++k) {
            const float4 b = *reinterpret_cast<const float4*>(&Bs[k][c0]);
            float av[4];
            #pragma unroll
            for (int i = 0; i < 4; ++i) av[i] = As[r0 + i][k];
            #pragma unroll
            for (int i = 0; i < 4; ++i) {
                acc[i][0] += av[i] * b.x;
                acc[i][1] += av[i] * b.y;
                acc[i][2] += av[i] * b.z;
                acc[i][3] += av[i] * b.w;
            }
        }
        __syncthreads();
    }
    // WhbT bf16, transposed [hf][n] so k3 B-fragments are 16B-contiguous
    #pragma unroll
    for (int j = 0; j < 4; ++j) {
        const int f = c0 + j;
        ushort4 w4;
        w4.x = f2bf_rne(acc[0][j]); w4.y = f2bf_rne(acc[1][j]);
        w4.z = f2bf_rne(acc[2][j]); w4.w = f2bf_rne(acc[3][j]);
        *reinterpret_cast<ushort4*>(&whbT[(size_t)(hf0 + f) * NN + n0 + r0]) = w4;
    }
    // e_src / e_dst from fp32 accumulators (accuracy anchor)
    float as4[4], ad4[4];
    #pragma unroll
    for (int j = 0; j < 4; ++j) { as4[j] = a_src[hf0 + c0 + j]; ad4[j] = a_dst[hf0 + c0 + j]; }
    #pragma unroll
    for (int i = 0; i < 4; ++i) {
        float ps = 0.f, pd = 0.f;
        #pragma unroll
        for (int j = 0; j < 4; ++j) { ps += acc[i][j] * as4[j]; pd += acc[i][j] * ad4[j]; }
        scrS[r0 + i][tid & 15] = ps;
        scrD[r0 + i][tid & 15] = pd;
    }
    __syncthreads();
    if (tid < 64) {
        float s = 0.f, d = 0.f;
        #pragma unroll
        for (int q = 0; q < 16; ++q) { s += scrS[tid][q]; d += scrD[tid][q]; }
        esrcT[hd * NN + n0 + tid] = s;
        edstT[hd * NN + n0 + tid] = d;
    }
}

// ---- k2: per-head max(e_dst) and the four exp tables ----
__global__ __launch_bounds__(256) void k2_tables(
        const float* __restrict__ esrcT, const float* __restrict__ edstT,
        float* __restrict__ es1T, float* __restrict__ es2T,
        float* __restrict__ ed1T, float* __restrict__ ed2T) {
    __shared__ float red[256];
    const int hd = blockIdx.x, tid = threadIdx.x;
    float m = -1e30f;
    for (int n = tid; n < NN; n += 256) m = fmaxf(m, edstT[hd * NN + n]);
    red[tid] = m;
    __syncthreads();
    for (int s = 128; s > 0; s >>= 1) {
        if (tid < s) red[tid] = fmaxf(red[tid], red[tid + s]);
        __syncthreads();
    }
    const float maxd = red[0];
    for (int n = tid; n < NN; n += 256) {
        const float ed = edstT[hd * NN + n];
        ed1T[hd * NN + n] = __expf(ed);
        ed2T[hd * NN + n] = __expf(0.2f * ed);
        const float es = esrcT[hd * NN + n];
        const float t  = es + maxd;
        const float M  = fmaxf(t, 0.2f * t);      // lrelu(es + max_j ed)  >= any score
        es1T[hd * NN + n] = __expf(es - M);
        es2T[hd * NN + n] = __expf(0.2f * es - M);
    }
}

// ---- k3: fused masked-softmax attention aggregation (one wave per head) ----
__global__ __launch_bounds__(512) void k3_attn(
        const int* __restrict__ adj, const unsigned short* __restrict__ whbT,
        const float* __restrict__ es1T, const float* __restrict__ es2T,
        const float* __restrict__ ed1T, const float* __restrict__ ed2T,
        float* __restrict__ numP, float* __restrict__ denP) {
    __shared__ uint32_t amask[BI][32];   // bf16-pair mask words, XOR-swizzled 16B blocks
    const int tid  = threadIdx.x;
    const int lane = tid & 63;
    const int wid  = tid >> 6;           // head
    const int iblk = blockIdx.x & 127;
    const int jc   = blockIdx.x >> 7;
    const int i0   = iblk * BI;
    const int jbase = jc * (NN / NC);
    const int g  = lane >> 4;
    const int lr = lane & 15;

    float es1[2], es2[2];
    #pragma unroll
    for (int mi = 0; mi < 2; ++mi) {
        es1[mi] = es1T[wid * NN + i0 + mi * 16 + lr];
        es2[mi] = es2T[wid * NN + i0 + mi * 16 + lr];
    }

    floatx4 acc[2][4] = {};
    floatx4 accd[2] = {};

    short8 ones;          // B fragment with column 0 = 1.0bf16 -> row-sum (denominator)
    {
        const short ov = (lr == 0) ? (short)0x3F80 : (short)0;
        #pragma unroll
        for (int e = 0; e < 8; ++e) ones[e] = ov;
    }

    for (int t = 0; t < NT; ++t) {
        const int j0 = jbase + t * JT;
        __syncthreads();
        {   // stage adj -> packed half-word masks (word w holds j-pair 2w,2w+1)
            const int r = tid >> 4, q = tid & 15;
            const int4 a = *reinterpret_cast<const int4*>(&adj[(size_t)(i0 + r) * NN + j0 + q * 4]);
            const uint32_t m0 = (a.x ? 0xFFFFu : 0u) | (a.y ? 0xFFFF0000u : 0u);
            const uint32_t m1 = (a.z ? 0xFFFFu : 0u) | (a.w ? 0xFFFF0000u : 0u);
            const int w0 = q * 2;
            const int p0 = (w0 & 3) | ((((w0 >> 2) ^ (r & 7)) & 7) << 2);
            amask[r][p0]     = m0;
            amask[r][p0 + 1] = m1;
        }
        __syncthreads();

        short8 bfrag[2][4];  // WhbT fragments: B[k=j, col=f]
        #pragma unroll
        for (int ks = 0; ks < 2; ++ks)
            #pragma unroll
            for (int ni = 0; ni < 4; ++ni)
                bfrag[ks][ni] = *reinterpret_cast<const short8*>(
                    &whbT[(size_t)(wid * FD + ni * 16 + lr) * NN + j0 + ks * 32 + g * 8]);

        #pragma unroll
        for (int ks = 0; ks < 2; ++ks) {
            const int jo = wid * NN + j0 + ks * 32 + g * 8;
            const float4 e1a = *reinterpret_cast<const float4*>(&ed1T[jo]);
            const float4 e1b = *reinterpret_cast<const float4*>(&ed1T[jo + 4]);
            const float4 e2a = *reinterpret_cast<const float4*>(&ed2T[jo]);
            const float4 e2b = *reinterpret_cast<const float4*>(&ed2T[jo + 4]);
            #pragma unroll
            for (int mi = 0; mi < 2; ++mi) {
                const int rr = mi * 16 + lr;
                const int pb = (((ks * 4 + g) ^ (lr & 7)) & 7) * 4;
                const uint4 msk = *reinterpret_cast<const uint4*>(&amask[rr][pb]);
                // p = max(ES1*ED1, ES2*ED2) == exp(lrelu(es+ed) - M); mask via half-word AND
                union { uint32_t w[4]; short8 s8; } pu;
                pu.w[0] = packtrunc(fmaxf(es1[mi] * e1a.x, es2[mi] * e2a.x),
                                    fmaxf(es1[mi] * e1a.y, es2[mi] * e2a.y)) & msk.x;
                pu.w[1] = packtrunc(fmaxf(es1[mi] * e1a.z, es2[mi] * e2a.z),
                                    fmaxf(es1[mi] * e1a.w, es2[mi] * e2a.w)) & msk.y;
                pu.w[2] = packtrunc(fmaxf(es1[mi] * e1b.x, es2[mi] * e2b.x),
                                    fmaxf(es1[mi] * e1b.y, es2[mi] * e2b.y)) & msk.z;
                pu.w[3] = packtrunc(fmaxf(es1[mi] * e1b.z, es2[mi] * e2b.z),
                                    fmaxf(es1[mi] * e1b.w, es2[mi] * e2b.w)) & msk.w;
                #pragma unroll
                for (int ni = 0; ni < 4; ++ni)
                    acc[mi][ni] = __builtin_amdgcn_mfma_f32_16x16x32_bf16(
                        pu.s8, bfrag[ks][ni], acc[mi][ni], 0, 0, 0);
                accd[mi] = __builtin_amdgcn_mfma_f32_16x16x32_bf16(
                        pu.s8, ones, accd[mi], 0, 0, 0);
            }
        }
    }

    // epilogue: C/D layout col=lane&15, row=(lane>>4)*4+reg
    #pragma unroll
    for (int mi = 0; mi < 2; ++mi) {
        #pragma unroll
        for (int ni = 0; ni < 4; ++ni) {
            #pragma unroll
            for (int r = 0; r < 4; ++r) {
                const int i = i0 + mi * 16 + g * 4 + r;
                numP[((size_t)jc * NN + i) * HFD + wid * FD + ni * 16 + lr] = acc[mi][ni][r];
            }
        }
        if (lr == 0) {
            #pragma unroll
            for (int r = 0; r < 4; ++r) {
                const int i = i0 + mi * 16 + g * 4 + r;
                denP[((size_t)jc * NH + wid) * NN + i] = accd[mi][r];
            }
        }
    }
}

// ---- k4: combine chunk partials, normalize, add bias ----
__global__ __launch_bounds__(256) void k4_reduce(
        const float* __restrict__ numP, const float* __restrict__ denP,
        const float* __restrict__ bias, float* __restrict__ out) {
    const int idx = blockIdx.x * 256 + threadIdx.x;
    const int e0 = idx * 4;
    const int i  = e0 >> 9;
    const int hf = e0 & 511;
    const int hd = hf >> 6;
    float4 s = make_float4(0.f, 0.f, 0.f, 0.f);
    float d = 0.f;
    #pragma unroll
    for (int c = 0; c < NC; ++c) {
        const float4 v = *reinterpret_cast<const float4*>(&numP[((size_t)c * NN + i) * HFD + hf]);
        s.x += v.x; s.y += v.y; s.z += v.z; s.w += v.w;
        d += denP[((size_t)c * NH + hd) * NN + i];
    }
    const float inv = 1.0f / d;
    const float4 b = *reinterpret_cast<const float4*>(&bias[hf]);
    float4 o;
    o.x = s.x * inv + b.x; o.y = s.y * inv + b.y;
    o.z = s.z * inv + b.z; o.w = s.w * inv + b.w;
    *reinterpret_cast<float4*>(&out[(size_t)i * HFD + hf]) = o;
}

extern "C" void kernel_launch(void* const* d_in, const int* in_sizes, int n_in,
                              void* d_out, int out_size, void* d_ws, size_t ws_size,
                              hipStream_t stream) {
    const float* hmat  = (const float*)d_in[0];
    const int*   adj   = (const int*)d_in[1];
    const float* Wmat  = (const float*)d_in[2];
    const float* a_src = (const float*)d_in[3];
    const float* a_dst = (const float*)d_in[4];
    const float* bias  = (const float*)d_in[5];
    float* out = (float*)d_out;

    char* ws = (char*)d_ws;
    unsigned short* whbT = (unsigned short*)ws;          // 4 MiB  (bf16 [HF][N])
    float* esrcT = (float*)(ws + (4u << 20));            // 6 x 128 KiB tables
    float* edstT = esrcT + NH * NN;
    float* es1T  = edstT + NH * NN;
    float* es2T  = es1T + NH * NN;
    float* ed1T  = es2T + NH * NN;
    float* ed2T  = ed1T + NH * NN;
    float* numP  = ed2T + NH * NN;                       // NC*N*HF fp32 = 16 MiB
    float* denP  = numP + (size_t)NC * NN * HFD;         // NC*H*N fp32 = 256 KiB

    k1_front<<<dim3(64, 8), 256, 0, stream>>>(hmat, Wmat, a_src, a_dst, whbT, esrcT, edstT);
    k2_tables<<<dim3(NH), 256, 0, stream>>>(esrcT, edstT, es1T, es2T, ed1T, ed2T);
    k3_attn<<<dim3(128 * NC), 512, 0, stream>>>(adj, whbT, es1T, es2T, ed1T, ed2T, numP, denP);
    k4_reduce<<<dim3((NN * HFD / 4) / 256), 256, 0, stream>>>(numP, denP, bias, out);
}